// Round 4
// baseline (109.869 us; speedup 1.0000x reference)
//
#include <hip/hip_runtime.h>

#define BN_EPS 1e-5f
#define WW 56
#define HWSZ 3136      // 56*56
#define TH 7           // output rows per block
#define THH 9          // TH + 2 halo rows

// One block = (batch b, 7-row tile). 32*8 = 256 blocks = 1 per CU.
// LDS: midA 120,960 + w1L 19,200 + w3T 19,200 + w2L 2,160 + sh 1,440 = 162,960 B.
__global__ __launch_bounds__(1024, 4) void fused_shufflenet_unit(
        const float* __restrict__ x,
        const float* __restrict__ w1, const float* __restrict__ g1,
        const float* __restrict__ b1, const float* __restrict__ m1,
        const float* __restrict__ v1,
        const float* __restrict__ w2, const float* __restrict__ g2,
        const float* __restrict__ b2, const float* __restrict__ m2,
        const float* __restrict__ v2,
        const float* __restrict__ w3, const float* __restrict__ g3,
        const float* __restrict__ b3, const float* __restrict__ m3,
        const float* __restrict__ v3,
        float* __restrict__ out) {
    __shared__ float midA[60 * THH * WW];   // stage1 out [60][9][56]; reused as md[60][7][56] (shuffled)
    __shared__ float w1L[60 * 80];          // [ch][ci], pre-scaled by s1
    __shared__ float w3T[20 * 240];         // [ci][cg], pre-scaled by s3
    __shared__ float w2L[60 * 9];           // pre-scaled by s2
    __shared__ float sh1[60], sh2[60], sh3[240];

    const int tid = threadIdx.x;
    const int b   = blockIdx.x >> 3;
    const int t   = blockIdx.x & 7;
    const int h0  = t * TH;

    // ---------- stage 0: stage weights, fold BN scales ----------
    for (int i = tid; i < 4800; i += 1024) {
        int ch = i / 80;
        w1L[i] = w1[i] * (g1[ch] * rsqrtf(v1[ch] + BN_EPS));
    }
    for (int i = tid; i < 4800; i += 1024) {
        int cg = i / 20, ci = i % 20;
        w3T[ci * 240 + cg] = w3[i] * (g3[cg] * rsqrtf(v3[cg] + BN_EPS));
    }
    for (int i = tid; i < 540; i += 1024) {
        int c = i / 9;
        w2L[i] = w2[i] * (g2[c] * rsqrtf(v2[c] + BN_EPS));
    }
    if (tid < 60) {
        float s1v = g1[tid] * rsqrtf(v1[tid] + BN_EPS);
        sh1[tid] = b1[tid] - m1[tid] * s1v;
        float s2v = g2[tid] * rsqrtf(v2[tid] + BN_EPS);
        sh2[tid] = b2[tid] - m2[tid] * s2v;
    }
    if (tid < 240) {
        float s3v = g3[tid] * rsqrtf(v3[tid] + BN_EPS);
        sh3[tid] = b3[tid] - m3[tid] * s3v;
    }
    __syncthreads();

    // ---------- stage 1: grouped conv1x1 (240->60) + BN1 + ReLU -> midA ----------
    // 756 items: item = chb*126 + (r*14 + c4); chb in [0,6) -> 10 mid-channels ch0=chb*10
    // (10 divides 20 -> all channels of an item are in the same input group)
    if (tid < 756) {
        const int chb = tid / 126;
        const int pr  = tid % 126;
        const int r = pr / 14, c4 = pr % 14;
        const int hh = h0 - 1 + r;
        const int ch0 = chb * 10;
        const int g = ch0 / 20;
        float4 acc[10];
#pragma unroll
        for (int c = 0; c < 10; c++) acc[c] = make_float4(0.f, 0.f, 0.f, 0.f);
        if (hh >= 0 && hh < 56) {
            const float* xp = x + ((size_t)(b * 240 + g * 80)) * HWSZ + hh * WW + c4 * 4;
#pragma unroll 2
            for (int ci4 = 0; ci4 < 20; ci4++) {
                float4 xv0 = *(const float4*)(xp + (ci4 * 4 + 0) * HWSZ);
                float4 xv1 = *(const float4*)(xp + (ci4 * 4 + 1) * HWSZ);
                float4 xv2 = *(const float4*)(xp + (ci4 * 4 + 2) * HWSZ);
                float4 xv3 = *(const float4*)(xp + (ci4 * 4 + 3) * HWSZ);
#pragma unroll
                for (int c = 0; c < 10; c++) {
                    float4 wv = *(const float4*)(w1L + (ch0 + c) * 80 + ci4 * 4);
                    acc[c].x += wv.x * xv0.x + wv.y * xv1.x + wv.z * xv2.x + wv.w * xv3.x;
                    acc[c].y += wv.x * xv0.y + wv.y * xv1.y + wv.z * xv2.y + wv.w * xv3.y;
                    acc[c].z += wv.x * xv0.z + wv.y * xv1.z + wv.z * xv2.z + wv.w * xv3.z;
                    acc[c].w += wv.x * xv0.w + wv.y * xv1.w + wv.z * xv2.w + wv.w * xv3.w;
                }
            }
#pragma unroll
            for (int c = 0; c < 10; c++) {
                float s = sh1[ch0 + c];
                acc[c].x = fmaxf(acc[c].x + s, 0.f);
                acc[c].y = fmaxf(acc[c].y + s, 0.f);
                acc[c].z = fmaxf(acc[c].z + s, 0.f);
                acc[c].w = fmaxf(acc[c].w + s, 0.f);
            }
        }
        // out-of-image rows stay zero (dw zero-padding)
#pragma unroll
        for (int c = 0; c < 10; c++) {
            *(float4*)(midA + ((ch0 + c) * THH + r) * WW + c4 * 4) = acc[c];
        }
    }
    __syncthreads();

    // ---------- stage 2: depthwise 3x3 + BN2 -> regs, then write back shuffled ----------
    // 5880 items: it = ch*98 + (r*14 + c4); out row r uses midA rows r, r+1, r+2
    float4 dwr[6];
#pragma unroll
    for (int k = 0; k < 6; k++) {
        const int it = tid + k * 1024;
        if (it < 5880) {
            const int ch = it / 98;
            const int pr = it % 98;
            const int r = pr / 14, c4 = pr % 14;
            const float* base = midA + ch * (THH * WW);
            const float* kw = w2L + ch * 9;
            float4 a = make_float4(0.f, 0.f, 0.f, 0.f);
#pragma unroll
            for (int dy = 0; dy < 3; dy++) {
                const float* row = base + (r + dy) * WW + c4 * 4;
                float4 m = *(const float4*)row;
                float l  = (c4 > 0)  ? row[-1] : 0.f;
                float rt = (c4 < 13) ? row[4]  : 0.f;
                const float k0 = kw[dy * 3 + 0];
                const float k1 = kw[dy * 3 + 1];
                const float k2 = kw[dy * 3 + 2];
                a.x += k0 * l   + k1 * m.x + k2 * m.y;
                a.y += k0 * m.x + k1 * m.y + k2 * m.z;
                a.z += k0 * m.y + k1 * m.z + k2 * m.w;
                a.w += k0 * m.z + k1 * m.w + k2 * rt;
            }
            const float s = sh2[ch];
            a.x += s; a.y += s; a.z += s; a.w += s;
            dwr[k] = a;
        }
    }
    __syncthreads();
    // write back channel-SHUFFLED: shuffled index jj s.t. shuffled[jj] = md[ch]
#pragma unroll
    for (int k = 0; k < 6; k++) {
        const int it = tid + k * 1024;
        if (it < 5880) {
            const int ch = it / 98;
            const int pr = it % 98;
            const int r = pr / 14, c4 = pr % 14;
            const int jj = (ch % 20) * 3 + ch / 20;
            *(float4*)(midA + (jj * TH + r) * WW + c4 * 4) = dwr[k];
        }
    }
    __syncthreads();

    // ---------- stage 3: grouped conv1x1 (60->240) + BN3 + ReLU + residual ----------
    // 5880 items: it = chb*98 + (r*14 + c4); chb in [0,60) -> 4 out-channels cg0=chb*4
    // group g = cg0/80; inputs are shuffled rows g*20..g*20+19 (contiguous in midA)
#pragma unroll
    for (int k = 0; k < 6; k++) {
        const int it = tid + k * 1024;
        if (it < 5880) {
            const int chb = it / 98;
            const int pr  = it % 98;
            const int r = pr / 14, c4 = pr % 14;
            const int cg0 = chb * 4;
            const int g = cg0 / 80;
            float4 acc[4];
#pragma unroll
            for (int c = 0; c < 4; c++) acc[c] = make_float4(0.f, 0.f, 0.f, 0.f);
            const float* mp0 = midA + (g * 20 * TH + r) * WW + c4 * 4;
#pragma unroll 4
            for (int ci = 0; ci < 20; ci++) {
                float4 mv = *(const float4*)(mp0 + ci * (TH * WW));
                float4 wv = *(const float4*)(w3T + ci * 240 + cg0);
                acc[0].x += wv.x * mv.x; acc[0].y += wv.x * mv.y; acc[0].z += wv.x * mv.z; acc[0].w += wv.x * mv.w;
                acc[1].x += wv.y * mv.x; acc[1].y += wv.y * mv.y; acc[1].z += wv.y * mv.z; acc[1].w += wv.y * mv.w;
                acc[2].x += wv.z * mv.x; acc[2].y += wv.z * mv.y; acc[2].z += wv.z * mv.z; acc[2].w += wv.z * mv.w;
                acc[3].x += wv.w * mv.x; acc[3].y += wv.w * mv.y; acc[3].z += wv.w * mv.z; acc[3].w += wv.w * mv.w;
            }
#pragma unroll
            for (int c = 0; c < 4; c++) {
                const int cg = cg0 + c;
                const float s = sh3[cg];
                const size_t off = ((size_t)(b * 240 + cg)) * HWSZ + (h0 + r) * WW + c4 * 4;
                float4 xr = *(const float4*)(x + off);
                float4 o;
                o.x = fmaxf(acc[c].x + s, 0.f) + xr.x;
                o.y = fmaxf(acc[c].y + s, 0.f) + xr.y;
                o.z = fmaxf(acc[c].z + s, 0.f) + xr.z;
                o.w = fmaxf(acc[c].w + s, 0.f) + xr.w;
                *(float4*)(out + off) = o;
            }
        }
    }
}

extern "C" void kernel_launch(void* const* d_in, const int* in_sizes, int n_in,
                              void* d_out, int out_size, void* d_ws, size_t ws_size,
                              hipStream_t stream) {
    const float* x  = (const float*)d_in[0];
    const float* w1 = (const float*)d_in[1];
    const float* g1 = (const float*)d_in[2];
    const float* b1 = (const float*)d_in[3];
    const float* m1 = (const float*)d_in[4];
    const float* v1 = (const float*)d_in[5];
    const float* w2 = (const float*)d_in[6];
    const float* g2 = (const float*)d_in[7];
    const float* b2 = (const float*)d_in[8];
    const float* m2 = (const float*)d_in[9];
    const float* v2 = (const float*)d_in[10];
    const float* w3 = (const float*)d_in[11];
    const float* g3 = (const float*)d_in[12];
    const float* b3 = (const float*)d_in[13];
    const float* m3 = (const float*)d_in[14];
    const float* v3 = (const float*)d_in[15];
    float* out = (float*)d_out;

    fused_shufflenet_unit<<<256, 1024, 0, stream>>>(
        x, w1, g1, b1, m1, v1, w2, g2, b2, m2, v2, w3, g3, b3, m3, v3, out);
}

// Round 5
// 84.165 us; speedup vs baseline: 1.3054x; 1.3054x over previous
//
#include <hip/hip_runtime.h>

#define BN_EPS 1e-5f
#define WW 56
#define HWSZ 3136      // 56*56
#define NB 32
#define CIN 240
#define MID 60
#define MIDG 20        // mid channels per group
#define COUT 240
#define COUTG 80
#define TH 7           // output rows per block (K_A)
#define THH 9          // TH + 2 halo rows

// ======== K_A: grouped conv1x1 (240->60) + BN1 + ReLU + depthwise 3x3 + BN2,
//          writing t2 already channel-shuffled. One block = (b, group, 7-row tile).
// Grid 32*3*8 = 768 blocks, 512 threads. LDS ~67 KB -> 2 blocks/CU (16 waves).
__global__ __launch_bounds__(512, 2) void kA_conv1_dw(
        const float* __restrict__ x,
        const float* __restrict__ w1, const float* __restrict__ g1,
        const float* __restrict__ b1, const float* __restrict__ m1,
        const float* __restrict__ v1,
        const float* __restrict__ w2, const float* __restrict__ g2,
        const float* __restrict__ b2, const float* __restrict__ m2,
        const float* __restrict__ v2,
        float* __restrict__ t2) {
    __shared__ float mid[MIDG * THH * WW];   // [20][9][56] = 40,320 B
    __shared__ float w1s[MIDG * 80];         // scaled, [c_local][ci] = 25,600 B
    __shared__ float w2s[MIDG * 9];          // scaled
    __shared__ float shA[MIDG], shB[MIDG];

    const int tid = threadIdx.x;
    const int bid = blockIdx.x;
    const int t   = bid & 7;
    const int gb  = bid >> 3;
    const int g   = gb % 3;
    const int b   = gb / 3;
    const int h0  = t * TH;

    // ---- stage 0: stage scaled weights ----
    for (int i = tid; i < MIDG * 80; i += 512) {
        int chg = g * MIDG + i / 80;
        w1s[i] = w1[chg * 80 + i % 80] * (g1[chg] * rsqrtf(v1[chg] + BN_EPS));
    }
    for (int i = tid; i < MIDG * 9; i += 512) {
        int chg = g * MIDG + i / 9;
        w2s[i] = w2[chg * 9 + i % 9] * (g2[chg] * rsqrtf(v2[chg] + BN_EPS));
    }
    if (tid < MIDG) {
        int chg = g * MIDG + tid;
        float s1v = g1[chg] * rsqrtf(v1[chg] + BN_EPS);
        shA[tid] = b1[chg] - m1[chg] * s1v;
        float s2v = g2[chg] * rsqrtf(v2[chg] + BN_EPS);
        shB[tid] = b2[chg] - m2[chg] * s2v;
    }
    __syncthreads();

    // ---- stage 1: conv1x1 for 20 channels x 9 rows -> mid ----
    // item: q = tid&3 (5-channel quarter), idx = tid>>2 < 126 -> (r, c4)
    {
        const int q   = tid & 3;
        const int idx = tid >> 2;
        if (idx < 126) {
            const int r  = idx / 14, c4 = idx % 14;
            const int hh = h0 - 1 + r;
            float4 acc[5];
#pragma unroll
            for (int c = 0; c < 5; c++) acc[c] = make_float4(0.f, 0.f, 0.f, 0.f);
            if (hh >= 0 && hh < 56) {
                const float* xp = x + ((size_t)(b * CIN + g * 80)) * HWSZ + hh * WW + c4 * 4;
                const float4* w4 = (const float4*)w1s;
#pragma unroll 4
                for (int ci4 = 0; ci4 < 20; ci4++) {
                    float4 xv0 = *(const float4*)(xp + (ci4 * 4 + 0) * HWSZ);
                    float4 xv1 = *(const float4*)(xp + (ci4 * 4 + 1) * HWSZ);
                    float4 xv2 = *(const float4*)(xp + (ci4 * 4 + 2) * HWSZ);
                    float4 xv3 = *(const float4*)(xp + (ci4 * 4 + 3) * HWSZ);
#pragma unroll
                    for (int c = 0; c < 5; c++) {
                        float4 wv = w4[(q * 5 + c) * 20 + ci4];
                        acc[c].x += wv.x * xv0.x + wv.y * xv1.x + wv.z * xv2.x + wv.w * xv3.x;
                        acc[c].y += wv.x * xv0.y + wv.y * xv1.y + wv.z * xv2.y + wv.w * xv3.y;
                        acc[c].z += wv.x * xv0.z + wv.y * xv1.z + wv.z * xv2.z + wv.w * xv3.z;
                        acc[c].w += wv.x * xv0.w + wv.y * xv1.w + wv.z * xv2.w + wv.w * xv3.w;
                    }
                }
#pragma unroll
                for (int c = 0; c < 5; c++) {
                    float s = shA[q * 5 + c];
                    acc[c].x = fmaxf(acc[c].x + s, 0.f);
                    acc[c].y = fmaxf(acc[c].y + s, 0.f);
                    acc[c].z = fmaxf(acc[c].z + s, 0.f);
                    acc[c].w = fmaxf(acc[c].w + s, 0.f);
                }
            }
#pragma unroll
            for (int c = 0; c < 5; c++)
                *(float4*)(mid + ((q * 5 + c) * THH + r) * WW + c4 * 4) = acc[c];
        }
    }
    __syncthreads();

    // ---- stage 2: depthwise 3x3 + BN2 -> t2 (channel-shuffled) ----
    // items: ch(20) x 98 quads, ch-major so stores are contiguous per channel-tile
#pragma unroll
    for (int k = 0; k < 4; k++) {
        const int it = tid + k * 512;
        if (it < MIDG * 98) {
            const int ch = it / 98;
            const int pq = it % 98;
            const int r = pq / 14, c4 = pq % 14;
            const float* base = mid + ch * (THH * WW);
            const float* kw = w2s + ch * 9;
            float4 a = make_float4(0.f, 0.f, 0.f, 0.f);
#pragma unroll
            for (int dy = 0; dy < 3; dy++) {
                const float* row = base + (r + dy) * WW + c4 * 4;
                float4 m = *(const float4*)row;
                float l  = (c4 > 0)  ? row[-1] : 0.f;
                float rt = (c4 < 13) ? row[4]  : 0.f;
                const float k0 = kw[dy * 3 + 0];
                const float k1 = kw[dy * 3 + 1];
                const float k2 = kw[dy * 3 + 2];
                a.x += k0 * l   + k1 * m.x + k2 * m.y;
                a.y += k0 * m.x + k1 * m.y + k2 * m.z;
                a.z += k0 * m.y + k1 * m.z + k2 * m.w;
                a.w += k0 * m.z + k1 * m.w + k2 * rt;
            }
            const float s = shB[ch];
            a.x += s; a.y += s; a.z += s; a.w += s;
            const int jj = ch * 3 + g;   // shuffled channel: S[ci*3+g] = mid[g*20+ci]
            *(float4*)(t2 + ((size_t)(b * MID + jj)) * HWSZ + (h0 + r) * WW + c4 * 4) = a;
        }
    }
}

// ======== K_B: grouped conv1x1 (60->240, inputs already shuffled) + BN3 + ReLU
//          + residual add. One thread: one float4 of positions, 20 out-channels
//          (q = item&3 -> lanes 0-3 share t2 loads, dedup'd in the coalescer).
__global__ __launch_bounds__(256) void kB_conv3_res(
        const float* __restrict__ t2, const float* __restrict__ w3,
        const float* __restrict__ g3, const float* __restrict__ b3,
        const float* __restrict__ m3, const float* __restrict__ v3,
        const float* __restrict__ x, float* __restrict__ out) {
    __shared__ float wT[3 * MIDG * COUTG];  // [g][ci][cg] : 4800 floats
    __shared__ float s3[COUT], sh3[COUT];
    const int tid = threadIdx.x;
    for (int i = tid; i < 3 * MIDG * COUTG; i += 256) {
        int co_glob = i / MIDG;     // row of w3
        int ci = i % MIDG;
        int gg = co_glob / COUTG;
        int cg = co_glob % COUTG;
        wT[(gg * MIDG + ci) * COUTG + cg] = w3[i];
    }
    if (tid < COUT) {
        float inv = g3[tid] * rsqrtf(v3[tid] + BN_EPS);
        s3[tid] = inv;
        sh3[tid] = b3[tid] - m3[tid] * inv;
    }
    __syncthreads();

    const int item = blockIdx.x * 256 + tid;  // < 301056
    const unsigned q  = (unsigned)item & 3u;  // out-channel quarter
    const unsigned pg = (unsigned)item >> 2;
    const unsigned p4 = pg % 784u;
    const unsigned bg = pg / 784u;
    const unsigned b = bg / 3u, g = bg % 3u;
    const int pos = (int)p4 * 4;

    float4 acc[MIDG];
#pragma unroll
    for (int c = 0; c < MIDG; c++) acc[c] = make_float4(0.f, 0.f, 0.f, 0.f);

    const float4* wl4 = (const float4*)wT;
#pragma unroll 4
    for (int ci = 0; ci < MIDG; ci++) {
        int csh = (int)g * MIDG + ci;          // t2 is already shuffled: read linearly
        float4 xv = *(const float4*)(t2 + ((size_t)(b * MID + csh)) * HWSZ + pos);
        int wbase = (csh * COUTG + q * MIDG) / 4;  // float4 index
#pragma unroll
        for (int k4 = 0; k4 < 5; k4++) {
            float4 wv = wl4[wbase + k4];
            acc[k4 * 4 + 0].x += wv.x * xv.x; acc[k4 * 4 + 0].y += wv.x * xv.y;
            acc[k4 * 4 + 0].z += wv.x * xv.z; acc[k4 * 4 + 0].w += wv.x * xv.w;
            acc[k4 * 4 + 1].x += wv.y * xv.x; acc[k4 * 4 + 1].y += wv.y * xv.y;
            acc[k4 * 4 + 1].z += wv.y * xv.z; acc[k4 * 4 + 1].w += wv.y * xv.w;
            acc[k4 * 4 + 2].x += wv.z * xv.x; acc[k4 * 4 + 2].y += wv.z * xv.y;
            acc[k4 * 4 + 2].z += wv.z * xv.z; acc[k4 * 4 + 2].w += wv.z * xv.w;
            acc[k4 * 4 + 3].x += wv.w * xv.x; acc[k4 * 4 + 3].y += wv.w * xv.y;
            acc[k4 * 4 + 3].z += wv.w * xv.z; acc[k4 * 4 + 3].w += wv.w * xv.w;
        }
    }

#pragma unroll
    for (int co = 0; co < MIDG; co++) {
        int cg = (int)g * COUTG + (int)q * MIDG + co;
        float sc = s3[cg], sf = sh3[cg];
        float4 xr = *(const float4*)(x + ((size_t)(b * CIN + cg)) * HWSZ + pos);
        float4 o;
        o.x = fmaxf(acc[co].x * sc + sf, 0.f) + xr.x;
        o.y = fmaxf(acc[co].y * sc + sf, 0.f) + xr.y;
        o.z = fmaxf(acc[co].z * sc + sf, 0.f) + xr.z;
        o.w = fmaxf(acc[co].w * sc + sf, 0.f) + xr.w;
        *(float4*)(out + ((size_t)(b * COUT + cg)) * HWSZ + pos) = o;
    }
}

extern "C" void kernel_launch(void* const* d_in, const int* in_sizes, int n_in,
                              void* d_out, int out_size, void* d_ws, size_t ws_size,
                              hipStream_t stream) {
    const float* x  = (const float*)d_in[0];
    const float* w1 = (const float*)d_in[1];
    const float* g1 = (const float*)d_in[2];
    const float* b1 = (const float*)d_in[3];
    const float* m1 = (const float*)d_in[4];
    const float* v1 = (const float*)d_in[5];
    const float* w2 = (const float*)d_in[6];
    const float* g2 = (const float*)d_in[7];
    const float* b2 = (const float*)d_in[8];
    const float* m2 = (const float*)d_in[9];
    const float* v2 = (const float*)d_in[10];
    const float* w3 = (const float*)d_in[11];
    const float* g3 = (const float*)d_in[12];
    const float* b3 = (const float*)d_in[13];
    const float* m3 = (const float*)d_in[14];
    const float* v3 = (const float*)d_in[15];
    float* out = (float*)d_out;

    float* t2 = (float*)d_ws;   // 32*60*3136 floats = 24 MB (shuffled dw output)

    // K_A: 32 b * 3 g * 8 tiles = 768 blocks
    kA_conv1_dw<<<768, 512, 0, stream>>>(x, w1, g1, b1, m1, v1,
                                         w2, g2, b2, m2, v2, t2);
    // K_B: 301056 threads / 256 = 1176 blocks
    kB_conv3_res<<<1176, 256, 0, stream>>>(t2, w3, g3, b3, m3, v3, x, out);
}